// Round 6
// baseline (288.730 us; speedup 1.0000x reference)
//
#include <hip/hip_runtime.h>

typedef __attribute__((ext_vector_type(8))) short bf16x8;
typedef __attribute__((ext_vector_type(4))) float f32x4;
typedef __attribute__((ext_vector_type(4))) unsigned short u16x4;

#define GPTR(p) (const __attribute__((address_space(1))) void*)(p)
#define LPTR(p) (__attribute__((address_space(3))) void*)(p)

static __device__ __forceinline__ unsigned short f2bf(float f) {
  union { float f; unsigned int u; } x; x.f = f;
  unsigned int u = x.u;
  unsigned int r = (u + 0x7fffu + ((u >> 16) & 1u)) >> 16;
  return (unsigned short)r;
}
static __device__ __forceinline__ float bf2f(unsigned short h) {
  union { unsigned int u; float f; } x; x.u = ((unsigned int)h) << 16;
  return x.f;
}
static __device__ __forceinline__ f32x4 f32x4_zero() {
  f32x4 z = {0.f, 0.f, 0.f, 0.f}; return z;
}
static __device__ __forceinline__ unsigned int cvt_pk_bf16(float lo, float hi) {
  unsigned int r;
  asm("v_cvt_pk_bf16_f32 %0, %1, %2" : "=v"(r) : "v"(lo), "v"(hi));
  return r;
}

// ---------------------------------------------------------------- RoPE table
__global__ void rope_table_kernel(float* __restrict__ costab, float* __restrict__ sintab) {
  int i = blockIdx.x * blockDim.x + threadIdx.x;   // 65536 total
  int s = i >> 5, d = i & 31;
  float invf = exp2f(-(float)d * (13.287712379549449f / 32.0f));
  float a = (float)s * invf;
  costab[i] = cosf(a);
  sintab[i] = sinf(a);
}

// ---------------------------------------------------------------- f32 -> bf16
__global__ void f32_to_bf16(const float* __restrict__ src, unsigned short* __restrict__ dst, int n4) {
  int stride = gridDim.x * blockDim.x;
  for (int i = blockIdx.x * blockDim.x + threadIdx.x; i < n4; i += stride) {
    float4 v = ((const float4*)src)[i];
    u16x4 o;
    o.x = f2bf(v.x); o.y = f2bf(v.y); o.z = f2bf(v.z); o.w = f2bf(v.w);
    *(u16x4*)(dst + (size_t)i * 4) = o;
  }
}

// ---------------------------------------------------------------- 8-wave 4-phase GEMM C = A @ B^T
template<int FM, int OUT_BF16>
__global__ __launch_bounds__(512, 2) void gemm8p(const unsigned short* __restrict__ A,
                                                 const unsigned short* __restrict__ B,
                                                 void* __restrict__ Cv,
                                                 int M, int N, int K, int nbx) {
  constexpr int BM = FM * 32;
  constexpr int MH = FM / 2;
  constexpr int ABYTES = BM * 128;      // per buffer
  constexpr int BBYTES = 256 * 128;
  __shared__ __align__(16) char lds_all[2 * ABYTES + 2 * BBYTES];
  char* lsA = lds_all;
  char* lsB = lds_all + 2 * ABYTES;

  const int tid = threadIdx.x;
  const int wave = tid >> 6, lane = tid & 63;
  const int fq = lane >> 4, fr = lane & 15;
  const int wr = wave >> 2, wc = wave & 3;

  // bijective XCD swizzle (gridDim.x % 8 == 0 by construction)
  const int nwg = gridDim.x;
  const int q8 = nwg >> 3;
  const int sw = (blockIdx.x & 7) * q8 + (blockIdx.x >> 3);
  const int by = sw / nbx;
  const int bx = sw - by * nbx;
  const int m0 = by * BM, n0 = bx * 256;

  const int arow = tid >> 3;
  const int scol = (((tid & 7) ^ (arow & 7)) << 4);   // pre-swizzled source col byte

#define STAGE_A(bufv, kt, h)                                                                  \
  do {                                                                                        \
    const char* src_ = (const char*)A + ((size_t)(m0 + (h) * 128 + arow) * K + (kt) * 64) * 2 + scol; \
    char* dst_ = lsA + (bufv) * ABYTES + (h) * 16384 + tid * 16;                              \
    __builtin_amdgcn_global_load_lds(GPTR(src_), LPTR(dst_), 16, 0, 0);                       \
    __builtin_amdgcn_global_load_lds(GPTR(src_ + (size_t)64 * K * 2), LPTR(dst_ + 8192), 16, 0, 0); \
  } while (0)
#define STAGE_B(bufv, kt, h)                                                                  \
  do {                                                                                        \
    const char* src_ = (const char*)B + ((size_t)(n0 + (h) * 128 + arow) * K + (kt) * 64) * 2 + scol; \
    char* dst_ = lsB + (bufv) * BBYTES + (h) * 16384 + tid * 16;                              \
    __builtin_amdgcn_global_load_lds(GPTR(src_), LPTR(dst_), 16, 0, 0);                       \
    __builtin_amdgcn_global_load_lds(GPTR(src_ + (size_t)64 * K * 2), LPTR(dst_ + 8192), 16, 0, 0); \
  } while (0)

  f32x4 acc[FM][4];
#pragma unroll
  for (int i = 0; i < FM; ++i)
#pragma unroll
    for (int j = 0; j < 4; ++j) acc[i][j] = f32x4_zero();

#define PHASE(p)                                                                              \
  do {                                                                                        \
    constexpr int mh = (p) >> 1, nh = (p) & 1;                                                \
    bf16x8 af[MH][2], bfv[2][2];                                                              \
    _Pragma("unroll") for (int m = 0; m < MH; ++m) {                                          \
      const int rowA = wr * FM * 16 + mh * MH * 16 + m * 16 + fr;                             \
      const char* pa = lsA + buf * ABYTES + (rowA >> 7) * 16384 + (rowA & 127) * 128;         \
      const int sz = (rowA & 7) << 4;                                                         \
      af[m][0] = *(const bf16x8*)(pa + ((fq * 16) ^ sz));                                     \
      af[m][1] = *(const bf16x8*)(pa + ((64 + fq * 16) ^ sz));                                \
    }                                                                                         \
    _Pragma("unroll") for (int n = 0; n < 2; ++n) {                                           \
      const int rowB = wc * 64 + nh * 32 + n * 16 + fr;                                       \
      const char* pb = lsB + buf * BBYTES + (rowB >> 7) * 16384 + (rowB & 127) * 128;         \
      const int sz = (rowB & 7) << 4;                                                         \
      bfv[n][0] = *(const bf16x8*)(pb + ((fq * 16) ^ sz));                                    \
      bfv[n][1] = *(const bf16x8*)(pb + ((64 + fq * 16) ^ sz));                               \
    }                                                                                         \
    asm volatile("s_waitcnt lgkmcnt(0)" ::: "memory");                                        \
    __builtin_amdgcn_sched_barrier(0);                                                        \
    __builtin_amdgcn_s_setprio(1);                                                            \
    _Pragma("unroll") for (int m = 0; m < MH; ++m)                                            \
      _Pragma("unroll") for (int n = 0; n < 2; ++n) {                                         \
        acc[mh * MH + m][nh * 2 + n] =                                                        \
            __builtin_amdgcn_mfma_f32_16x16x32_bf16(af[m][0], bfv[n][0], acc[mh * MH + m][nh * 2 + n], 0, 0, 0); \
        acc[mh * MH + m][nh * 2 + n] =                                                        \
            __builtin_amdgcn_mfma_f32_16x16x32_bf16(af[m][1], bfv[n][1], acc[mh * MH + m][nh * 2 + n], 0, 0, 0); \
      }                                                                                       \
    __builtin_amdgcn_s_setprio(0);                                                            \
  } while (0)

  const int NT = K >> 6;

  STAGE_A(0, 0, 0);
  if constexpr (FM == 8) STAGE_A(0, 0, 1);
  STAGE_B(0, 0, 0);
  STAGE_B(0, 0, 1);
  asm volatile("s_waitcnt vmcnt(0)" ::: "memory");
  __builtin_amdgcn_s_barrier();

  int buf = 0;
  for (int t = 0; t < NT; ++t) {
    const bool hn = (t + 1) < NT;
    if (hn) {
      STAGE_A(buf ^ 1, t + 1, 0);
      asm volatile("s_waitcnt vmcnt(2)" ::: "memory");
    } else {
      asm volatile("s_waitcnt vmcnt(0)" ::: "memory");
    }
    __builtin_amdgcn_s_barrier();
    PHASE(0);
    __builtin_amdgcn_s_barrier();
    if (hn) {
      if constexpr (FM == 8) STAGE_A(buf ^ 1, t + 1, 1);
      else                   STAGE_B(buf ^ 1, t + 1, 0);
    }
    PHASE(1);
    __builtin_amdgcn_s_barrier();
    if (hn) {
      if constexpr (FM == 8) STAGE_B(buf ^ 1, t + 1, 0);
      else                   STAGE_B(buf ^ 1, t + 1, 1);
    }
    PHASE(2);
    __builtin_amdgcn_s_barrier();
    if (hn) {
      if constexpr (FM == 8) STAGE_B(buf ^ 1, t + 1, 1);
    }
    PHASE(3);
    __builtin_amdgcn_s_barrier();
    buf ^= 1;
  }

#pragma unroll
  for (int i = 0; i < FM; ++i) {
    const int row = m0 + wr * FM * 16 + i * 16 + fq * 4;
#pragma unroll
    for (int j = 0; j < 4; ++j) {
      const int col = n0 + wc * 64 + j * 16 + fr;
#pragma unroll
      for (int v = 0; v < 4; ++v) {
        if (OUT_BF16) ((unsigned short*)Cv)[(size_t)(row + v) * N + col] = f2bf(acc[i][j][v]);
        else          ((float*)Cv)[(size_t)(row + v) * N + col] = acc[i][j][v];
      }
    }
  }
#undef STAGE_A
#undef STAGE_B
#undef PHASE
}

// ---------------------------------------------------------------- RoPE in-place on qkv
__global__ void rope_kernel(unsigned short* __restrict__ qkv,
                            const float* __restrict__ costab,
                            const float* __restrict__ sintab) {
  int idx = blockIdx.x * blockDim.x + threadIdx.x;
  if (idx >= 4096 * 1280) return;
  int row = idx / 1280;
  int p = idx - row * 1280;
  int s = row & 2047;
  int col, d; bool isq;
  if (p < 1024) { isq = true;  d = p & 31; col = (p >> 5) * 64 + d; }
  else { isq = false; int pk = p - 1024; d = pk & 31; col = 2048 + (pk >> 5) * 64 + d; }
  float c = costab[s * 32 + d], sn = sintab[s * 32 + d];
  unsigned short* base = qkv + (size_t)row * 3072;
  float x1 = bf2f(base[col]), x2 = bf2f(base[col + 32]);
  float o1 = x1 * c - x2 * sn;
  float o2 = x1 * sn + x2 * c;
  if (isq) { o1 *= 0.18033688011112042f; o2 *= 0.18033688011112042f; }  // 0.125*log2(e)
  base[col] = f2bf(o1);
  base[col + 32] = f2bf(o2);
}

// ---------------------------------------------------------------- flash attention (8-wave, dbuf)
// 1-D grid of 512. Remap: c=id&255, w=id>>8, hb=c&63 (h=hb&31, b=hb>>5),
// qhalf=c>>6, qt = w ? qhalf : 7-qhalf.
//  - CU pairs (id, id+256) get complementary qt -> every CU does 36 steps (balanced)
//  - id%8 == hb%8 -> all q-tiles of a head-batch on one XCD (KV L2 reuse)
//  - long blocks (qt>=4) dispatch first
__global__ __launch_bounds__(512, 4) void flash_attn(const unsigned short* __restrict__ qkv,
                                                     unsigned short* __restrict__ out) {
  __shared__ __align__(16) char K_sh[2 * 8192];
  __shared__ __align__(16) char V_sh[2 * 8192];
  __shared__ __align__(16) char P_sh[8 * 4096];

  const int tid = threadIdx.x;
  const int wave = tid >> 6, lane = tid & 63;
  const int fq = lane >> 4, fr = lane & 15;
  const int id = blockIdx.x;
  const int w = id >> 8, c = id & 255;
  const int hb = c & 63;
  const int h = hb & 31, b = hb >> 5;
  const int qhalf = c >> 6;
  const int qt = w ? qhalf : 7 - qhalf;
  const int kvh = h >> 2;
  const int q0 = qt * 256;
  const int wq0 = q0 + wave * 32;
  char* Pw = P_sh + wave * 4096;

  bf16x8 qreg[2][2];
#pragma unroll
  for (int qf = 0; qf < 2; ++qf)
#pragma unroll
    for (int kk = 0; kk < 2; ++kk)
      qreg[qf][kk] = *(const bf16x8*)(qkv + (size_t)(b * 2048 + wq0 + qf * 16 + fr) * 3072
                                      + h * 64 + kk * 32 + fq * 8);

  f32x4 o_acc[4][2];
  float m_run[2], l_run[2];
#pragma unroll
  for (int dc = 0; dc < 4; ++dc) { o_acc[dc][0] = f32x4_zero(); o_acc[dc][1] = f32x4_zero(); }
  m_run[0] = m_run[1] = -1e30f;
  l_run[0] = l_run[1] = 0.f;

  const char* kgbase = (const char*)qkv + (size_t)(b * 2048) * 6144 + 4096 + kvh * 128;
  const unsigned short* vgbase = qkv + (size_t)(b * 2048) * 3072 + 2560 + kvh * 64;
  const int nsteps = (q0 + 256) >> 6;

  const int vk2 = (tid >> 3) << 1;
  const int vc0 = (tid & 7) << 3;
  const int kt = tid - 256;

  {
    if (wave < 4) {
      bf16x8 vv0 = *(const bf16x8*)(vgbase + (size_t)vk2 * 3072 + vc0);
      bf16x8 vv1 = *(const bf16x8*)(vgbase + (size_t)(vk2 + 1) * 3072 + vc0);
#pragma unroll
      for (int j = 0; j < 8; ++j) {
        const int d = vc0 + j;
        const int G = ((d & 7) ^ (d >> 3)) & 7;
        unsigned int w2 = ((unsigned int)(unsigned short)vv0[j]) |
                          (((unsigned int)(unsigned short)vv1[j]) << 16);
        *(unsigned int*)(V_sh + (d << 7) + ((vk2 << 1) ^ (G << 4))) = w2;
      }
    } else {
#pragma unroll
      for (int ld = 0; ld < 2; ++ld) {
        const int row = (kt >> 3) + (ld << 5);
        const int cb = ((kt & 7) << 4) ^ ((row & 7) << 4);
        __builtin_amdgcn_global_load_lds(GPTR(kgbase + (size_t)row * 6144 + cb),
                                         LPTR(K_sh + kt * 16 + ld * 4096), 16, 0, 0);
      }
    }
  }
  __syncthreads();

  int buf = 0;
  for (int st = 0; st < nsteps; ++st) {
    const int k0 = st << 6;
    const bool has_next = (st + 1) < nsteps;
    bf16x8 vv0, vv1;
    if (has_next) {
      const int k0n = k0 + 64;
      if (wave < 4) {
        vv0 = *(const bf16x8*)(vgbase + (size_t)(k0n + vk2) * 3072 + vc0);
        vv1 = *(const bf16x8*)(vgbase + (size_t)(k0n + vk2 + 1) * 3072 + vc0);
      } else {
        char* Kn = K_sh + (buf ^ 1) * 8192;
#pragma unroll
        for (int ld = 0; ld < 2; ++ld) {
          const int row = (kt >> 3) + (ld << 5);
          const int cb = ((kt & 7) << 4) ^ ((row & 7) << 4);
          __builtin_amdgcn_global_load_lds(GPTR(kgbase + (size_t)(k0n + row) * 6144 + cb),
                                           LPTR(Kn + kt * 16 + ld * 4096), 16, 0, 0);
        }
      }
    }

    if (k0 <= wq0 + 31) {
      const char* Kb = K_sh + buf * 8192;
      const char* Vb = V_sh + buf * 8192;
      f32x4 s[2][4];
#pragma unroll
      for (int qf = 0; qf < 2; ++qf)
#pragma unroll
        for (int kf = 0; kf < 4; ++kf) s[qf][kf] = f32x4_zero();
#pragma unroll
      for (int kf = 0; kf < 4; ++kf) {
        const int krow = kf * 16 + fr;
        const int swz = (krow & 7) << 4;
        bf16x8 ka = *(const bf16x8*)(Kb + krow * 128 + ((fq * 16) ^ swz));
        bf16x8 kb = *(const bf16x8*)(Kb + krow * 128 + ((64 + fq * 16) ^ swz));
#pragma unroll
        for (int qf = 0; qf < 2; ++qf) {
          s[qf][kf] = __builtin_amdgcn_mfma_f32_16x16x32_bf16(ka, qreg[qf][0], s[qf][kf], 0, 0, 0);
          s[qf][kf] = __builtin_amdgcn_mfma_f32_16x16x32_bf16(kb, qreg[qf][1], s[qf][kf], 0, 0, 0);
        }
      }
      if (k0 + 63 > wq0) {
#pragma unroll
        for (int qf = 0; qf < 2; ++qf) {
          const int q = wq0 + qf * 16 + fr;
#pragma unroll
          for (int kf = 0; kf < 4; ++kf)
#pragma unroll
            for (int v = 0; v < 4; ++v) {
              const int key = k0 + kf * 16 + fq * 4 + v;
              if (key > q) s[qf][kf][v] = -1e30f;
            }
        }
      }
#pragma unroll
      for (int qf = 0; qf < 2; ++qf) {
        float t = s[qf][0][0];
#pragma unroll
        for (int kf = 0; kf < 4; ++kf)
#pragma unroll
          for (int v = 0; v < 4; ++v) t = fmaxf(t, s[qf][kf][v]);
        t = fmaxf(t, __shfl_xor(t, 16));
        t = fmaxf(t, __shfl_xor(t, 32));
        const float mo = m_run[qf];
        const float mn = fmaxf(mo, t);
        const float sc = __builtin_amdgcn_exp2f(mo - mn);
        m_run[qf] = mn;
        float ps = 0.f;
#pragma unroll
        for (int kf = 0; kf < 4; ++kf)
#pragma unroll
          for (int v = 0; v < 4; ++v) {
            const float p = __builtin_amdgcn_exp2f(s[qf][kf][v] - mn);
            s[qf][kf][v] = p;
            ps += p;
          }
        ps += __shfl_xor(ps, 16);
        ps += __shfl_xor(ps, 32);
        l_run[qf] = l_run[qf] * sc + ps;
#pragma unroll
        for (int dc = 0; dc < 4; ++dc) o_acc[dc][qf] *= sc;
        const int r = qf * 16 + fr;
        const int rswz = (r & 7) << 4;
#pragma unroll
        for (int kf = 0; kf < 4; ++kf) {
          uint2 w2;
          w2.x = cvt_pk_bf16(s[qf][kf][0], s[qf][kf][1]);
          w2.y = cvt_pk_bf16(s[qf][kf][2], s[qf][kf][3]);
          *(uint2*)(Pw + r * 128 + ((kf * 32 + fq * 8) ^ rswz)) = w2;
        }
      }
      asm volatile("s_waitcnt lgkmcnt(0)" ::: "memory");
      __builtin_amdgcn_sched_barrier(0);
      const int fswz = (fr & 7) << 4;
#pragma unroll
      for (int kk = 0; kk < 2; ++kk) {
        bf16x8 pa0 = *(const bf16x8*)(Pw + fr * 128 + ((kk * 64 + fq * 16) ^ fswz));
        bf16x8 pa1 = *(const bf16x8*)(Pw + (16 + fr) * 128 + ((kk * 64 + fq * 16) ^ fswz));
#pragma unroll
        for (int dc = 0; dc < 4; ++dc) {
          const int d = dc * 16 + fr;
          const int G = ((d & 7) ^ (d >> 3)) & 7;
          bf16x8 vt = *(const bf16x8*)(Vb + d * 128 + ((kk * 64 + fq * 16) ^ (G << 4)));
          o_acc[dc][0] = __builtin_amdgcn_mfma_f32_16x16x32_bf16(vt, pa0, o_acc[dc][0], 0, 0, 0);
          o_acc[dc][1] = __builtin_amdgcn_mfma_f32_16x16x32_bf16(vt, pa1, o_acc[dc][1], 0, 0, 0);
        }
      }
    }

    if (has_next && wave < 4) {
      char* Vn = V_sh + (buf ^ 1) * 8192;
#pragma unroll
      for (int j = 0; j < 8; ++j) {
        const int d = vc0 + j;
        const int G = ((d & 7) ^ (d >> 3)) & 7;
        unsigned int w2 = ((unsigned int)(unsigned short)vv0[j]) |
                          (((unsigned int)(unsigned short)vv1[j]) << 16);
        *(unsigned int*)(Vn + (d << 7) + ((vk2 << 1) ^ (G << 4))) = w2;
      }
    }
    __syncthreads();
    buf ^= 1;
  }

#pragma unroll
  for (int qf = 0; qf < 2; ++qf) {
    const float inv = 1.0f / l_run[qf];
    const size_t row = (size_t)(b * 2048 + wq0 + qf * 16 + fr);
#pragma unroll
    for (int dc = 0; dc < 4; ++dc) {
      u16x4 o;
#pragma unroll
      for (int v = 0; v < 4; ++v) o[v] = f2bf(o_acc[dc][qf][v] * inv);
      *(u16x4*)(out + row * 2048 + h * 64 + dc * 16 + fq * 4) = o;
    }
  }
}

// ---------------------------------------------------------------- launch
extern "C" void kernel_launch(void* const* d_in, const int* in_sizes, int n_in,
                              void* d_out, int out_size, void* d_ws, size_t ws_size,
                              hipStream_t stream) {
  (void)in_sizes; (void)n_in; (void)out_size; (void)ws_size;
  const float* x  = (const float*)d_in[0];
  const float* wq = (const float*)d_in[1];
  const float* wk = (const float*)d_in[2];
  const float* wv = (const float*)d_in[3];
  const float* wo = (const float*)d_in[4];

  char* wsb = (char*)d_ws;
  unsigned short* xb     = (unsigned short*)(wsb);
  unsigned short* attn_o = xb;
  unsigned short* wqkvb  = (unsigned short*)(wsb + 16777216);
  unsigned short* wob    = (unsigned short*)(wsb + 29360128);
  unsigned short* qkv    = (unsigned short*)(wsb + 37748736);
  float* costab          = (float*)(wsb + 62914560);
  float* sintab          = (float*)(wsb + 63176704);

  rope_table_kernel<<<256, 256, 0, stream>>>(costab, sintab);

  f32_to_bf16<<<2048, 256, 0, stream>>>(x,  xb,                 8388608 / 4);
  f32_to_bf16<<<1024, 256, 0, stream>>>(wq, wqkvb,              4194304 / 4);
  f32_to_bf16<<<256,  256, 0, stream>>>(wk, wqkvb + 4194304,    1048576 / 4);
  f32_to_bf16<<<256,  256, 0, stream>>>(wv, wqkvb + 5242880,    1048576 / 4);
  f32_to_bf16<<<1024, 256, 0, stream>>>(wo, wob,                4194304 / 4);

  // qkv = x @ [wq;wk;wv]^T : M=4096, N=3072, K=2048 ; 192 blocks (16x12)
  gemm8p<8, 1><<<192, 512, 0, stream>>>(xb, wqkvb, (void*)qkv, 4096, 3072, 2048, 12);

  rope_kernel<<<20480, 256, 0, stream>>>(qkv, costab, sintab);

  flash_attn<<<512, 512, 0, stream>>>(qkv, attn_o);

  // out = attn @ wo^T : M=4096, N=2048, K=2048 ; 256 blocks (32x8)
  gemm8p<4, 0><<<256, 512, 0, stream>>>(attn_o, wob, d_out, 4096, 2048, 2048, 8);
}

// Round 7
// 271.760 us; speedup vs baseline: 1.0624x; 1.0624x over previous
//
#include <hip/hip_runtime.h>

typedef __attribute__((ext_vector_type(8))) short bf16x8;
typedef __attribute__((ext_vector_type(4))) float f32x4;
typedef __attribute__((ext_vector_type(4))) unsigned short u16x4;

#define GPTR(p) (const __attribute__((address_space(1))) void*)(p)
#define LPTR(p) (__attribute__((address_space(3))) void*)(p)

static __device__ __forceinline__ unsigned short f2bf(float f) {
  union { float f; unsigned int u; } x; x.f = f;
  unsigned int u = x.u;
  unsigned int r = (u + 0x7fffu + ((u >> 16) & 1u)) >> 16;
  return (unsigned short)r;
}
static __device__ __forceinline__ float bf2f(unsigned short h) {
  union { unsigned int u; float f; } x; x.u = ((unsigned int)h) << 16;
  return x.f;
}
static __device__ __forceinline__ f32x4 f32x4_zero() {
  f32x4 z = {0.f, 0.f, 0.f, 0.f}; return z;
}
static __device__ __forceinline__ unsigned int cvt_pk_bf16(float lo, float hi) {
  unsigned int r;
  asm("v_cvt_pk_bf16_f32 %0, %1, %2" : "=v"(r) : "v"(lo), "v"(hi));
  return r;
}

// ---------------------------------------------------------------- RoPE table
__global__ void rope_table_kernel(float* __restrict__ costab, float* __restrict__ sintab) {
  int i = blockIdx.x * blockDim.x + threadIdx.x;   // 65536 total
  int s = i >> 5, d = i & 31;
  float invf = exp2f(-(float)d * (13.287712379549449f / 32.0f));
  float a = (float)s * invf;
  costab[i] = cosf(a);
  sintab[i] = sinf(a);
}

// ---------------------------------------------------------------- f32 -> bf16
__global__ void f32_to_bf16(const float* __restrict__ src, unsigned short* __restrict__ dst, int n4) {
  int stride = gridDim.x * blockDim.x;
  for (int i = blockIdx.x * blockDim.x + threadIdx.x; i < n4; i += stride) {
    float4 v = ((const float4*)src)[i];
    u16x4 o;
    o.x = f2bf(v.x); o.y = f2bf(v.y); o.z = f2bf(v.z); o.w = f2bf(v.w);
    *(u16x4*)(dst + (size_t)i * 4) = o;
  }
}

// ---------------------------------------------------------------- 8-wave 4-phase GEMM C = A @ B^T
template<int FM, int OUT_BF16>
__global__ __launch_bounds__(512, 2) void gemm8p(const unsigned short* __restrict__ A,
                                                 const unsigned short* __restrict__ B,
                                                 void* __restrict__ Cv,
                                                 int M, int N, int K, int nbx) {
  constexpr int BM = FM * 32;
  constexpr int MH = FM / 2;
  constexpr int ABYTES = BM * 128;      // per buffer
  constexpr int BBYTES = 256 * 128;
  __shared__ __align__(16) char lds_all[2 * ABYTES + 2 * BBYTES];
  char* lsA = lds_all;
  char* lsB = lds_all + 2 * ABYTES;

  const int tid = threadIdx.x;
  const int wave = tid >> 6, lane = tid & 63;
  const int fq = lane >> 4, fr = lane & 15;
  const int wr = wave >> 2, wc = wave & 3;

  // bijective XCD swizzle (gridDim.x % 8 == 0 by construction)
  const int nwg = gridDim.x;
  const int q8 = nwg >> 3;
  const int sw = (blockIdx.x & 7) * q8 + (blockIdx.x >> 3);
  const int by = sw / nbx;
  const int bx = sw - by * nbx;
  const int m0 = by * BM, n0 = bx * 256;

  const int arow = tid >> 3;
  const int scol = (((tid & 7) ^ (arow & 7)) << 4);   // pre-swizzled source col byte

#define STAGE_A(bufv, kt, h)                                                                  \
  do {                                                                                        \
    const char* src_ = (const char*)A + ((size_t)(m0 + (h) * 128 + arow) * K + (kt) * 64) * 2 + scol; \
    char* dst_ = lsA + (bufv) * ABYTES + (h) * 16384 + tid * 16;                              \
    __builtin_amdgcn_global_load_lds(GPTR(src_), LPTR(dst_), 16, 0, 0);                       \
    __builtin_amdgcn_global_load_lds(GPTR(src_ + (size_t)64 * K * 2), LPTR(dst_ + 8192), 16, 0, 0); \
  } while (0)
#define STAGE_B(bufv, kt, h)                                                                  \
  do {                                                                                        \
    const char* src_ = (const char*)B + ((size_t)(n0 + (h) * 128 + arow) * K + (kt) * 64) * 2 + scol; \
    char* dst_ = lsB + (bufv) * BBYTES + (h) * 16384 + tid * 16;                              \
    __builtin_amdgcn_global_load_lds(GPTR(src_), LPTR(dst_), 16, 0, 0);                       \
    __builtin_amdgcn_global_load_lds(GPTR(src_ + (size_t)64 * K * 2), LPTR(dst_ + 8192), 16, 0, 0); \
  } while (0)

  f32x4 acc[FM][4];
#pragma unroll
  for (int i = 0; i < FM; ++i)
#pragma unroll
    for (int j = 0; j < 4; ++j) acc[i][j] = f32x4_zero();

#define PHASE(p)                                                                              \
  do {                                                                                        \
    constexpr int mh = (p) >> 1, nh = (p) & 1;                                                \
    bf16x8 af[MH][2], bfv[2][2];                                                              \
    _Pragma("unroll") for (int m = 0; m < MH; ++m) {                                          \
      const int rowA = wr * FM * 16 + mh * MH * 16 + m * 16 + fr;                             \
      const char* pa = lsA + buf * ABYTES + (rowA >> 7) * 16384 + (rowA & 127) * 128;         \
      const int sz = (rowA & 7) << 4;                                                         \
      af[m][0] = *(const bf16x8*)(pa + ((fq * 16) ^ sz));                                     \
      af[m][1] = *(const bf16x8*)(pa + ((64 + fq * 16) ^ sz));                                \
    }                                                                                         \
    _Pragma("unroll") for (int n = 0; n < 2; ++n) {                                           \
      const int rowB = wc * 64 + nh * 32 + n * 16 + fr;                                       \
      const char* pb = lsB + buf * BBYTES + (rowB >> 7) * 16384 + (rowB & 127) * 128;         \
      const int sz = (rowB & 7) << 4;                                                         \
      bfv[n][0] = *(const bf16x8*)(pb + ((fq * 16) ^ sz));                                    \
      bfv[n][1] = *(const bf16x8*)(pb + ((64 + fq * 16) ^ sz));                               \
    }                                                                                         \
    asm volatile("s_waitcnt lgkmcnt(0)" ::: "memory");                                        \
    __builtin_amdgcn_sched_barrier(0);                                                        \
    __builtin_amdgcn_s_setprio(1);                                                            \
    _Pragma("unroll") for (int m = 0; m < MH; ++m)                                            \
      _Pragma("unroll") for (int n = 0; n < 2; ++n) {                                         \
        acc[mh * MH + m][nh * 2 + n] =                                                        \
            __builtin_amdgcn_mfma_f32_16x16x32_bf16(af[m][0], bfv[n][0], acc[mh * MH + m][nh * 2 + n], 0, 0, 0); \
        acc[mh * MH + m][nh * 2 + n] =                                                        \
            __builtin_amdgcn_mfma_f32_16x16x32_bf16(af[m][1], bfv[n][1], acc[mh * MH + m][nh * 2 + n], 0, 0, 0); \
      }                                                                                       \
    __builtin_amdgcn_s_setprio(0);                                                            \
  } while (0)

  const int NT = K >> 6;

  STAGE_A(0, 0, 0);
  if constexpr (FM == 8) STAGE_A(0, 0, 1);
  STAGE_B(0, 0, 0);
  STAGE_B(0, 0, 1);
  asm volatile("s_waitcnt vmcnt(0)" ::: "memory");
  __builtin_amdgcn_s_barrier();

  int buf = 0;
  for (int t = 0; t < NT; ++t) {
    const bool hn = (t + 1) < NT;
    if (hn) {
      STAGE_A(buf ^ 1, t + 1, 0);
      asm volatile("s_waitcnt vmcnt(2)" ::: "memory");
    } else {
      asm volatile("s_waitcnt vmcnt(0)" ::: "memory");
    }
    __builtin_amdgcn_s_barrier();
    PHASE(0);
    __builtin_amdgcn_s_barrier();
    if (hn) {
      if constexpr (FM == 8) STAGE_A(buf ^ 1, t + 1, 1);
      else                   STAGE_B(buf ^ 1, t + 1, 0);
    }
    PHASE(1);
    __builtin_amdgcn_s_barrier();
    if (hn) {
      if constexpr (FM == 8) STAGE_B(buf ^ 1, t + 1, 0);
      else                   STAGE_B(buf ^ 1, t + 1, 1);
    }
    PHASE(2);
    __builtin_amdgcn_s_barrier();
    if (hn) {
      if constexpr (FM == 8) STAGE_B(buf ^ 1, t + 1, 1);
    }
    PHASE(3);
    __builtin_amdgcn_s_barrier();
    buf ^= 1;
  }

#pragma unroll
  for (int i = 0; i < FM; ++i) {
    const int row = m0 + wr * FM * 16 + i * 16 + fq * 4;
#pragma unroll
    for (int j = 0; j < 4; ++j) {
      const int col = n0 + wc * 64 + j * 16 + fr;
#pragma unroll
      for (int v = 0; v < 4; ++v) {
        if (OUT_BF16) ((unsigned short*)Cv)[(size_t)(row + v) * N + col] = f2bf(acc[i][j][v]);
        else          ((float*)Cv)[(size_t)(row + v) * N + col] = acc[i][j][v];
      }
    }
  }
#undef STAGE_A
#undef STAGE_B
#undef PHASE
}

// ---------------------------------------------------------------- RoPE in-place on qkv
__global__ void rope_kernel(unsigned short* __restrict__ qkv,
                            const float* __restrict__ costab,
                            const float* __restrict__ sintab) {
  int idx = blockIdx.x * blockDim.x + threadIdx.x;
  if (idx >= 4096 * 1280) return;
  int row = idx / 1280;
  int p = idx - row * 1280;
  int s = row & 2047;
  int col, d; bool isq;
  if (p < 1024) { isq = true;  d = p & 31; col = (p >> 5) * 64 + d; }
  else { isq = false; int pk = p - 1024; d = pk & 31; col = 2048 + (pk >> 5) * 64 + d; }
  float c = costab[s * 32 + d], sn = sintab[s * 32 + d];
  unsigned short* base = qkv + (size_t)row * 3072;
  float x1 = bf2f(base[col]), x2 = bf2f(base[col + 32]);
  float o1 = x1 * c - x2 * sn;
  float o2 = x1 * sn + x2 * c;
  if (isq) { o1 *= 0.18033688011112042f; o2 *= 0.18033688011112042f; }  // 0.125*log2(e)
  base[col] = f2bf(o1);
  base[col + 32] = f2bf(o2);
}

// ---------------------------------------------------------------- flash attention (8-wave, dbuf)
// Round-5 mapping (measured 126us): qt = 7-(id&7) (long first, same-qt blocks
// share XCD + CU pairing), h=(id>>3)&31, b=id>>8.
// Softmax: pairwise-tree max/sum reductions (shorten dependent chain) and
// T13 defer-max (skip m-update + rescale unless pmax - m > 11.5 in exp2 units).
__global__ __launch_bounds__(512, 4) void flash_attn(const unsigned short* __restrict__ qkv,
                                                     unsigned short* __restrict__ out) {
  __shared__ __align__(16) char K_sh[2 * 8192];
  __shared__ __align__(16) char V_sh[2 * 8192];
  __shared__ __align__(16) char P_sh[8 * 4096];

  const int tid = threadIdx.x;
  const int wave = tid >> 6, lane = tid & 63;
  const int fq = lane >> 4, fr = lane & 15;
  const int id = blockIdx.x;
  const int qt = 7 - (id & 7);
  const int h = (id >> 3) & 31;
  const int b = id >> 8;
  const int kvh = h >> 2;
  const int q0 = qt * 256;
  const int wq0 = q0 + wave * 32;
  char* Pw = P_sh + wave * 4096;

  bf16x8 qreg[2][2];
#pragma unroll
  for (int qf = 0; qf < 2; ++qf)
#pragma unroll
    for (int kk = 0; kk < 2; ++kk)
      qreg[qf][kk] = *(const bf16x8*)(qkv + (size_t)(b * 2048 + wq0 + qf * 16 + fr) * 3072
                                      + h * 64 + kk * 32 + fq * 8);

  f32x4 o_acc[4][2];
  float m_run[2], l_run[2];
#pragma unroll
  for (int dc = 0; dc < 4; ++dc) { o_acc[dc][0] = f32x4_zero(); o_acc[dc][1] = f32x4_zero(); }
  m_run[0] = m_run[1] = -1e30f;
  l_run[0] = l_run[1] = 0.f;

  const char* kgbase = (const char*)qkv + (size_t)(b * 2048) * 6144 + 4096 + kvh * 128;
  const unsigned short* vgbase = qkv + (size_t)(b * 2048) * 3072 + 2560 + kvh * 64;
  const int nsteps = (q0 + 256) >> 6;

  const int vk2 = (tid >> 3) << 1;
  const int vc0 = (tid & 7) << 3;
  const int kt = tid - 256;

  {
    if (wave < 4) {
      bf16x8 vv0 = *(const bf16x8*)(vgbase + (size_t)vk2 * 3072 + vc0);
      bf16x8 vv1 = *(const bf16x8*)(vgbase + (size_t)(vk2 + 1) * 3072 + vc0);
#pragma unroll
      for (int j = 0; j < 8; ++j) {
        const int d = vc0 + j;
        const int G = ((d & 7) ^ (d >> 3)) & 7;
        unsigned int w2 = ((unsigned int)(unsigned short)vv0[j]) |
                          (((unsigned int)(unsigned short)vv1[j]) << 16);
        *(unsigned int*)(V_sh + (d << 7) + ((vk2 << 1) ^ (G << 4))) = w2;
      }
    } else {
#pragma unroll
      for (int ld = 0; ld < 2; ++ld) {
        const int row = (kt >> 3) + (ld << 5);
        const int cb = ((kt & 7) << 4) ^ ((row & 7) << 4);
        __builtin_amdgcn_global_load_lds(GPTR(kgbase + (size_t)row * 6144 + cb),
                                         LPTR(K_sh + kt * 16 + ld * 4096), 16, 0, 0);
      }
    }
  }
  __syncthreads();

  int buf = 0;
  for (int st = 0; st < nsteps; ++st) {
    const int k0 = st << 6;
    const bool has_next = (st + 1) < nsteps;
    bf16x8 vv0, vv1;
    if (has_next) {
      const int k0n = k0 + 64;
      if (wave < 4) {
        vv0 = *(const bf16x8*)(vgbase + (size_t)(k0n + vk2) * 3072 + vc0);
        vv1 = *(const bf16x8*)(vgbase + (size_t)(k0n + vk2 + 1) * 3072 + vc0);
      } else {
        char* Kn = K_sh + (buf ^ 1) * 8192;
#pragma unroll
        for (int ld = 0; ld < 2; ++ld) {
          const int row = (kt >> 3) + (ld << 5);
          const int cb = ((kt & 7) << 4) ^ ((row & 7) << 4);
          __builtin_amdgcn_global_load_lds(GPTR(kgbase + (size_t)(k0n + row) * 6144 + cb),
                                           LPTR(Kn + kt * 16 + ld * 4096), 16, 0, 0);
        }
      }
    }

    if (k0 <= wq0 + 31) {
      const char* Kb = K_sh + buf * 8192;
      const char* Vb = V_sh + buf * 8192;
      f32x4 s[2][4];
#pragma unroll
      for (int qf = 0; qf < 2; ++qf)
#pragma unroll
        for (int kf = 0; kf < 4; ++kf) s[qf][kf] = f32x4_zero();
#pragma unroll
      for (int kf = 0; kf < 4; ++kf) {
        const int krow = kf * 16 + fr;
        const int swz = (krow & 7) << 4;
        bf16x8 ka = *(const bf16x8*)(Kb + krow * 128 + ((fq * 16) ^ swz));
        bf16x8 kb = *(const bf16x8*)(Kb + krow * 128 + ((64 + fq * 16) ^ swz));
#pragma unroll
        for (int qf = 0; qf < 2; ++qf) {
          s[qf][kf] = __builtin_amdgcn_mfma_f32_16x16x32_bf16(ka, qreg[qf][0], s[qf][kf], 0, 0, 0);
          s[qf][kf] = __builtin_amdgcn_mfma_f32_16x16x32_bf16(kb, qreg[qf][1], s[qf][kf], 0, 0, 0);
        }
      }
      if (k0 + 63 > wq0) {
#pragma unroll
        for (int qf = 0; qf < 2; ++qf) {
          const int q = wq0 + qf * 16 + fr;
#pragma unroll
          for (int kf = 0; kf < 4; ++kf)
#pragma unroll
            for (int v = 0; v < 4; ++v) {
              const int key = k0 + kf * 16 + fq * 4 + v;
              if (key > q) s[qf][kf][v] = -1e30f;
            }
        }
      }
      // ---- tree max per qf (4-level pairwise, then 2 shfl)
      float pm[2];
#pragma unroll
      for (int qf = 0; qf < 2; ++qf) {
        float a0 = fmaxf(fmaxf(s[qf][0][0], s[qf][0][1]), fmaxf(s[qf][0][2], s[qf][0][3]));
        float a1 = fmaxf(fmaxf(s[qf][1][0], s[qf][1][1]), fmaxf(s[qf][1][2], s[qf][1][3]));
        float a2 = fmaxf(fmaxf(s[qf][2][0], s[qf][2][1]), fmaxf(s[qf][2][2], s[qf][2][3]));
        float a3 = fmaxf(fmaxf(s[qf][3][0], s[qf][3][1]), fmaxf(s[qf][3][2], s[qf][3][3]));
        float t = fmaxf(fmaxf(a0, a1), fmaxf(a2, a3));
        t = fmaxf(t, __shfl_xor(t, 16));
        t = fmaxf(t, __shfl_xor(t, 32));
        pm[qf] = t;
      }
      // ---- T13 defer-max: rescale only when max grew by > 11.5 (exp2 units)
      if (__any(fmaxf(pm[0] - m_run[0], pm[1] - m_run[1]) > 11.5f)) {
#pragma unroll
        for (int qf = 0; qf < 2; ++qf) {
          const float mn = fmaxf(m_run[qf], pm[qf]);
          const float sc = __builtin_amdgcn_exp2f(m_run[qf] - mn);
          m_run[qf] = mn;
          l_run[qf] *= sc;
#pragma unroll
          for (int dc = 0; dc < 4; ++dc) o_acc[dc][qf] *= sc;
        }
      }
      // ---- exp2 + tree sum + P pack
#pragma unroll
      for (int qf = 0; qf < 2; ++qf) {
        const float mn = m_run[qf];
#pragma unroll
        for (int kf = 0; kf < 4; ++kf)
#pragma unroll
          for (int v = 0; v < 4; ++v)
            s[qf][kf][v] = __builtin_amdgcn_exp2f(s[qf][kf][v] - mn);
        float b0 = (s[qf][0][0] + s[qf][0][1]) + (s[qf][0][2] + s[qf][0][3]);
        float b1 = (s[qf][1][0] + s[qf][1][1]) + (s[qf][1][2] + s[qf][1][3]);
        float b2 = (s[qf][2][0] + s[qf][2][1]) + (s[qf][2][2] + s[qf][2][3]);
        float b3 = (s[qf][3][0] + s[qf][3][1]) + (s[qf][3][2] + s[qf][3][3]);
        float ps = (b0 + b1) + (b2 + b3);
        ps += __shfl_xor(ps, 16);
        ps += __shfl_xor(ps, 32);
        l_run[qf] += ps;
        const int r = qf * 16 + fr;
        const int rswz = (r & 7) << 4;
#pragma unroll
        for (int kf = 0; kf < 4; ++kf) {
          uint2 w2;
          w2.x = cvt_pk_bf16(s[qf][kf][0], s[qf][kf][1]);
          w2.y = cvt_pk_bf16(s[qf][kf][2], s[qf][kf][3]);
          *(uint2*)(Pw + r * 128 + ((kf * 32 + fq * 8) ^ rswz)) = w2;
        }
      }
      asm volatile("s_waitcnt lgkmcnt(0)" ::: "memory");
      __builtin_amdgcn_sched_barrier(0);
      const int fswz = (fr & 7) << 4;
#pragma unroll
      for (int kk = 0; kk < 2; ++kk) {
        bf16x8 pa0 = *(const bf16x8*)(Pw + fr * 128 + ((kk * 64 + fq * 16) ^ fswz));
        bf16x8 pa1 = *(const bf16x8*)(Pw + (16 + fr) * 128 + ((kk * 64 + fq * 16) ^ fswz));
#pragma unroll
        for (int dc = 0; dc < 4; ++dc) {
          const int d = dc * 16 + fr;
          const int G = ((d & 7) ^ (d >> 3)) & 7;
          bf16x8 vt = *(const bf16x8*)(Vb + d * 128 + ((kk * 64 + fq * 16) ^ (G << 4)));
          o_acc[dc][0] = __builtin_amdgcn_mfma_f32_16x16x32_bf16(vt, pa0, o_acc[dc][0], 0, 0, 0);
          o_acc[dc][1] = __builtin_amdgcn_mfma_f32_16x16x32_bf16(vt, pa1, o_acc[dc][1], 0, 0, 0);
        }
      }
    }

    if (has_next && wave < 4) {
      char* Vn = V_sh + (buf ^ 1) * 8192;
#pragma unroll
      for (int j = 0; j < 8; ++j) {
        const int d = vc0 + j;
        const int G = ((d & 7) ^ (d >> 3)) & 7;
        unsigned int w2 = ((unsigned int)(unsigned short)vv0[j]) |
                          (((unsigned int)(unsigned short)vv1[j]) << 16);
        *(unsigned int*)(Vn + (d << 7) + ((vk2 << 1) ^ (G << 4))) = w2;
      }
    }
    __syncthreads();
    buf ^= 1;
  }

#pragma unroll
  for (int qf = 0; qf < 2; ++qf) {
    const float inv = 1.0f / l_run[qf];
    const size_t row = (size_t)(b * 2048 + wq0 + qf * 16 + fr);
#pragma unroll
    for (int dc = 0; dc < 4; ++dc) {
      u16x4 o;
#pragma unroll
      for (int v = 0; v < 4; ++v) o[v] = f2bf(o_acc[dc][qf][v] * inv);
      *(u16x4*)(out + row * 2048 + h * 64 + dc * 16 + fq * 4) = o;
    }
  }
}

// ---------------------------------------------------------------- launch
extern "C" void kernel_launch(void* const* d_in, const int* in_sizes, int n_in,
                              void* d_out, int out_size, void* d_ws, size_t ws_size,
                              hipStream_t stream) {
  (void)in_sizes; (void)n_in; (void)out_size; (void)ws_size;
  const float* x  = (const float*)d_in[0];
  const float* wq = (const float*)d_in[1];
  const float* wk = (const float*)d_in[2];
  const float* wv = (const float*)d_in[3];
  const float* wo = (const float*)d_in[4];

  char* wsb = (char*)d_ws;
  unsigned short* xb     = (unsigned short*)(wsb);
  unsigned short* attn_o = xb;
  unsigned short* wqkvb  = (unsigned short*)(wsb + 16777216);
  unsigned short* wob    = (unsigned short*)(wsb + 29360128);
  unsigned short* qkv    = (unsigned short*)(wsb + 37748736);
  float* costab          = (float*)(wsb + 62914560);
  float* sintab          = (float*)(wsb + 63176704);

  rope_table_kernel<<<256, 256, 0, stream>>>(costab, sintab);

  f32_to_bf16<<<2048, 256, 0, stream>>>(x,  xb,                 8388608 / 4);
  f32_to_bf16<<<1024, 256, 0, stream>>>(wq, wqkvb,              4194304 / 4);
  f32_to_bf16<<<256,  256, 0, stream>>>(wk, wqkvb + 4194304,    1048576 / 4);
  f32_to_bf16<<<256,  256, 0, stream>>>(wv, wqkvb + 5242880,    1048576 / 4);
  f32_to_bf16<<<1024, 256, 0, stream>>>(wo, wob,                4194304 / 4);

  // qkv = x @ [wq;wk;wv]^T : M=4096, N=3072, K=2048 ; 192 blocks (16x12)
  gemm8p<8, 1><<<192, 512, 0, stream>>>(xb, wqkvb, (void*)qkv, 4096, 3072, 2048, 12);

  rope_kernel<<<20480, 256, 0, stream>>>(qkv, costab, sintab);

  flash_attn<<<512, 512, 0, stream>>>(qkv, attn_o);

  // out = attn @ wo^T : M=4096, N=2048, K=2048 ; 256 blocks (32x8)
  gemm8p<4, 0><<<256, 512, 0, stream>>>(attn_o, wob, d_out, 4096, 2048, 2048, 8);
}